// Round 7
// baseline (250.311 us; speedup 1.0000x reference)
//
#include <hip/hip_runtime.h>
#include <stdint.h>

#define B_N   16384
#define S_N   256
#define NCH   8
#define P_N   (B_N * S_N)      // 4194304 positions (b,s)
#define EPS_F 1e-5f

typedef float  f32x4  __attribute__((ext_vector_type(4)));
typedef float  f32x16 __attribute__((ext_vector_type(16)));
typedef __bf16 bf16x8 __attribute__((ext_vector_type(8)));
typedef __bf16 bf16x4 __attribute__((ext_vector_type(4)));
typedef unsigned int u32x4 __attribute__((ext_vector_type(4)));
typedef unsigned int u32x2 __attribute__((ext_vector_type(2)));

static __device__ __forceinline__ unsigned short f2bf(float f) {
  union { float f; unsigned u; } v; v.f = f;
  unsigned u = v.u;
  u += 0x7fffu + ((u >> 16) & 1u);          // RNE
  return (unsigned short)(u >> 16);
}
static __device__ __forceinline__ float bf2f(unsigned short h) {
  union { unsigned u; float f; } v; v.u = ((unsigned)h) << 16;
  return v.f;
}

typedef const __attribute__((address_space(1))) unsigned int* gas1_t;
typedef __attribute__((address_space(3))) unsigned int* las3_t;
// async global->LDS, 16B per lane; LDS dest must be linear (base + lane*16)
static __device__ __forceinline__ void gl16(const void* g, void* l) {
  __builtin_amdgcn_global_load_lds((gas1_t)(uintptr_t)g,
                                   (las3_t)(unsigned int)(uintptr_t)l, 16, 0, 0);
}

// ---------------- pass 1: per-channel stats partials + planar bf16 transpose ----------------
__global__ __launch_bounds__(256) void pass1_kernel(
    const float* __restrict__ x, unsigned short* __restrict__ xplan,
    float* __restrict__ partials)
{
  __shared__ float ps[4][32];
  const int t = threadIdx.x;
  const int q = t & 3;               // channel quad: interleaved channels 4q..4q+3
  const int pg = t >> 2;             // 0..63 position-group within tile
  float s[4] = {0.f,0.f,0.f,0.f}, ss[4] = {0.f,0.f,0.f,0.f};
  const f32x4* xv = (const f32x4*)x;

  for (int it = 0; it < 4; ++it) {
    size_t p0 = ((size_t)blockIdx.x * 4 + it) * 512 + (size_t)pg * 8;
    f32x4 v[8];
    #pragma unroll
    for (int j = 0; j < 8; ++j) v[j] = xv[(p0 + j) * 4 + q];
    #pragma unroll
    for (int j = 0; j < 8; ++j)
      #pragma unroll
      for (int k = 0; k < 4; ++k) { s[k] += v[j][k]; ss[k] += v[j][k] * v[j][k]; }
    #pragma unroll
    for (int j2 = 0; j2 < 4; ++j2) {
      u32x4 w;
      #pragma unroll
      for (int k = 0; k < 4; ++k)
        w[k] = (unsigned)f2bf(v[2*k][j2]) | ((unsigned)f2bf(v[2*k+1][j2]) << 16);
      *(u32x4*)(xplan + (size_t)(q * 4 + j2) * P_N + p0) = w;
    }
  }

  #pragma unroll
  for (int off = 32; off >= 4; off >>= 1) {
    #pragma unroll
    for (int k = 0; k < 4; ++k) { s[k] += __shfl_down(s[k], off); ss[k] += __shfl_down(ss[k], off); }
  }
  const int lane = t & 63, wid = t >> 6;
  if (lane < 4) {
    #pragma unroll
    for (int k = 0; k < 4; ++k) {
      ps[wid][lane * 4 + k]      = s[k];
      ps[wid][16 + lane * 4 + k] = ss[k];
    }
  }
  __syncthreads();
  if (t < 32)
    partials[blockIdx.x * 32 + t] = ps[0][t] + ps[1][t] + ps[2][t] + ps[3][t];
}

// ---------------- finalize: reduce partials -> A,C ----------------
__global__ __launch_bounds__(1024) void finalize_kernel(
    const float* __restrict__ partials, const float* __restrict__ g_in,
    const float* __restrict__ b_in, float* __restrict__ AC)
{
  __shared__ float acc[32][32];
  const int t = threadIdx.x;
  const int v = t & 31, chunk = t >> 5;
  float s = 0.f;
  for (int i = 0; i < 64; ++i)
    s += partials[(size_t)(chunk * 64 + i) * 32 + v];
  acc[chunk][v] = s;
  __syncthreads();
  if (t < 32) {
    float tot = 0.f;
    #pragma unroll
    for (int k = 0; k < 32; ++k) tot += acc[k][t];
    acc[0][t] = tot;
  }
  __syncthreads();
  if (t < 16) {
    float n = (float)P_N;
    float mu  = acc[0][t] / n;
    float var = acc[0][16 + t] / n - mu * mu;
    float A = g_in[t] * rsqrtf(var + EPS_F);
    AC[t] = A;
    AC[16 + t] = b_in[t] - mu * A;
  }
}

// ---------------- W prep: fp32 -> bf16 chunk-granule layout + rowsums ----------------
// wp[c][u8][o256][g8][j8]; granule g = ks*4 + ty*2 + kh holds k = u*32+ks*16+kh*8+j,
// type ty (0=Wr,1=Wi). One 128B row per (c,u,o).
__global__ __launch_bounds__(256) void wprep_kernel(
    const float* __restrict__ Wr, const float* __restrict__ Wi,
    unsigned short* __restrict__ wp,
    float* __restrict__ RWr, float* __restrict__ RWi)
{
  __shared__ float sr[4], si[4];
  const int row = blockIdx.x, t = threadIdx.x;   // row = c*256 + o, t = k
  const int c = row >> 8, o = row & 255;
  const size_t idx = (size_t)row * 256 + t;
  float vr = Wr[idx], vi = Wi[idx];
  const int u = t >> 5, k5 = t & 31;
  const int ks = k5 >> 4, kh = (k5 >> 3) & 1, j = t & 7;
  const size_t base = (((size_t)(c * 8 + u) * 256 + o) << 6) + (ks * 4 + kh) * 8 + j;
  wp[base]      = f2bf(vr);    // ty=0 (Wr): granule ks*4+0+kh
  wp[base + 16] = f2bf(vi);    // ty=1 (Wi): granule ks*4+2+kh  (+2 granules = +16 elems)
  float rr = vr, ri = vi;
  #pragma unroll
  for (int off = 32; off >= 1; off >>= 1) { rr += __shfl_down(rr, off); ri += __shfl_down(ri, off); }
  if ((t & 63) == 0) { sr[t >> 6] = rr; si[t >> 6] = ri; }
  __syncthreads();
  if (t == 0) {
    RWr[row] = sr[0] + sr[1] + sr[2] + sr[3];
    RWi[row] = si[0] + si[1] + si[2] + si[3];
  }
}

// ---------------- K terms ----------------
__global__ __launch_bounds__(256) void kterm_kernel(
    const float* __restrict__ AC, const float* __restrict__ RWr, const float* __restrict__ RWi,
    float* __restrict__ Kr, float* __restrict__ Ki)
{
  int idx = blockIdx.x * 256 + threadIdx.x;   // 2048 = c*256+o
  int c = idx >> 8;
  float Ci_ = AC[16 + 2*c], Cq_ = AC[16 + 2*c + 1];
  Kr[idx] = Ci_ * RWr[idx] - Cq_ * RWi[idx];
  Ki[idx] = Cq_ * RWr[idx] + Ci_ * RWi[idx];
}

// ---------------- main: 32x32x16 MFMA; A from global (L1-hot), W via dbuf LDS ----------------
// 512 blocks x 256 thr (4 waves, each owns 64 o); M=32 rows/block; 2 blocks/CU (LDS 80KB).
__global__ __launch_bounds__(256, 2) void main_kernel(
    const unsigned short* __restrict__ xplan,
    const unsigned short* __restrict__ wp,
    const float* __restrict__ AC,
    const float* __restrict__ Kr, const float* __restrict__ Ki,
    const float* __restrict__ Wfr, const float* __restrict__ Wfi,
    float* __restrict__ y)
{
  __shared__ char smem[81920];  // [0,64K): W dbuf 2x32KB; [64K,80K): amp2s[32][256] bf16
  unsigned short* amp2s = (unsigned short*)(smem + 65536);
  float (*red)[32][2] = (float(*)[32][2])smem;   // alias after final sync

  const int t = threadIdx.x;
  const int wid = t >> 6, lane = t & 63;
  const int o31 = lane & 31, kh = lane >> 5;
  const int b0 = blockIdx.x * 32;
  const int so = t >> 3, sslot = t & 7;          // W staging coords
  const int arow = t >> 3, aoq = t & 7;          // amp2 coords

  float pC0[16], pC1[16];
  #pragma unroll
  for (int i = 0; i < 16; ++i) { pC0[i] = 0.f; pC1[i] = 0.f; }

  // prologue: stage W(c=0,u=0) into buf 0
  {
    const char* base = (const char*)wp;
    #pragma unroll
    for (int i = 0; i < 8; ++i) {
      const int o = i * 32 + so;
      const int g = sslot ^ (o & 7);
      gl16(base + o * 128 + g * 16, smem + i * 4096 + t * 16);
    }
  }

  #pragma unroll 1
  for (int c = 0; c < NCH; ++c) {
    const float Ai_ = AC[2*c],      Aq_ = AC[2*c + 1];
    const float Cin = AC[16 + 2*c], Cqn = AC[16 + 2*c + 1];
    f32x16 acc[2][4];   // [ot][ty*2+pl]
    #pragma unroll
    for (int ot = 0; ot < 2; ++ot)
      #pragma unroll
      for (int m = 0; m < 4; ++m)
        #pragma unroll
        for (int e = 0; e < 16; ++e) acc[ot][m][e] = 0.f;

    #pragma unroll 1
    for (int u = 0; u < 8; ++u) {
      const int p = c * 8 + u;
      asm volatile("s_waitcnt vmcnt(0)" ::: "memory");   // W(p) landed (only thing in flight)
      __builtin_amdgcn_s_barrier();                      // W(p) visible; buf (p+1)&1 free

      // --- A fragments + amp2 inputs: direct global (issue BEFORE gl16 so their
      //     auto-waitcnt doesn't drain the W prefetch) ---
      bf16x8 a[2][2];   // [pl][ks]
      #pragma unroll
      for (int pl = 0; pl < 2; ++pl) {
        const unsigned short* xr = xplan + (size_t)(2*c + pl) * P_N
                                 + (size_t)(b0 + o31) * 256 + u * 32 + kh * 8;
        a[pl][0] = *(const bf16x8*)(xr);
        a[pl][1] = *(const bf16x8*)(xr + 16);
      }
      const size_t abase = (size_t)(2*c) * P_N + (size_t)(b0 + arow) * 256 + u * 32 + aoq * 4;
      bf16x4 xi4 = *(const bf16x4*)(xplan + abase);
      bf16x4 xq4 = *(const bf16x4*)(xplan + abase + P_N);
      __builtin_amdgcn_sched_barrier(0);

      // --- prefetch W(p+1) ---
      if (p + 1 < 64) {
        const int cn = (p + 1) >> 3, un = (p + 1) & 7;
        const char* base = (const char*)wp + ((size_t)(cn * 8 + un) << 15);
        char* buf = smem + ((p + 1) & 1) * 32768;
        #pragma unroll
        for (int i = 0; i < 8; ++i) {
          const int o = i * 32 + so;
          const int g = sslot ^ (o & 7);
          gl16(base + o * 128 + g * 16, buf + i * 4096 + t * 16);
        }
      }
      __builtin_amdgcn_sched_barrier(0);

      // --- B fragments from LDS ---
      const char* Wb = smem + (p & 1) * 32768;
      bf16x8 b[2][2][2];   // [ot][ty][ks]
      #pragma unroll
      for (int ot = 0; ot < 2; ++ot) {
        const int o = wid * 64 + ot * 32 + o31;
        #pragma unroll
        for (int ty = 0; ty < 2; ++ty)
          #pragma unroll
          for (int ks = 0; ks < 2; ++ks) {
            const int g = ks * 4 + ty * 2 + kh;
            b[ot][ty][ks] = *(const bf16x8*)(Wb + o * 128 + ((g ^ (o & 7)) << 4));
          }
      }

      __builtin_amdgcn_s_setprio(1);
      #pragma unroll
      for (int ks = 0; ks < 2; ++ks)
        #pragma unroll
        for (int ot = 0; ot < 2; ++ot)
          #pragma unroll
          for (int ty = 0; ty < 2; ++ty)
            #pragma unroll
            for (int pl = 0; pl < 2; ++pl)
              acc[ot][ty*2 + pl] = __builtin_amdgcn_mfma_f32_32x32x16_bf16(
                  a[pl][ks], b[ot][ty][ks], acc[ot][ty*2 + pl], 0, 0, 0);
      __builtin_amdgcn_s_setprio(0);

      // --- amp2 slice for this chunk's 32 o-positions ---
      {
        unsigned short w4[4];
        #pragma unroll
        for (int e = 0; e < 4; ++e) {
          float xiv = Ai_ * (float)xi4[e] + Cin;
          float xqv = Aq_ * (float)xq4[e] + Cqn;
          w4[e] = f2bf(xiv * xiv + xqv * xqv);
        }
        u32x2 pw;
        pw[0] = (unsigned)w4[0] | ((unsigned)w4[1] << 16);
        pw[1] = (unsigned)w4[2] | ((unsigned)w4[3] << 16);
        *(u32x2*)((char*)amp2s + arow * 512 + u * 64 + aoq * 8) = pw;
      }
    }

    // --- channel epilogue ---
    asm volatile("s_waitcnt lgkmcnt(0)" ::: "memory");   // amp2 stores landed
    __builtin_amdgcn_s_barrier();                        // all slices visible
    #pragma unroll
    for (int ot = 0; ot < 2; ++ot) {
      const int o = wid * 64 + ot * 32 + o31;
      const int gidx = c * 256 + o;
      const float kr = Kr[gidx], ki = Ki[gidx];
      const float wfr = Wfr[gidx], wfi = Wfi[gidx];
      #pragma unroll
      for (int q = 0; q < 16; ++q) {
        const int brow = (q & 3) + 8 * (q >> 2) + 4 * kh;   // m74/m101 C/D row
        float amp = bf2f(amp2s[brow * 256 + o]);
        float cr = Ai_ * acc[ot][0][q] - Aq_ * acc[ot][3][q] + kr;
        float ci = Aq_ * acc[ot][1][q] + Ai_ * acc[ot][2][q] + ki;
        pC0[q] += amp * (cr * wfr - ci * wfi);
        pC1[q] += amp * (ci * wfr + cr * wfi);
      }
    }
  }

  // reduce over the 32 o-columns within each half-wave (halves hold different rows)
  #pragma unroll
  for (int off = 1; off < 32; off <<= 1) {
    #pragma unroll
    for (int q = 0; q < 16; ++q) {
      pC0[q] += __shfl_xor(pC0[q], off);
      pC1[q] += __shfl_xor(pC1[q], off);
    }
  }
  __syncthreads();   // full drain: safe to alias smem as red
  if (o31 == 0) {
    #pragma unroll
    for (int q = 0; q < 16; ++q) {
      const int brow = (q & 3) + 8 * (q >> 2) + 4 * kh;
      red[wid][brow][0] = pC0[q];
      red[wid][brow][1] = pC1[q];
    }
  }
  __syncthreads();
  if (t < 64) {
    const int row = t >> 1, cc = t & 1;
    y[(size_t)(b0 + row) * 2 + cc] =
        red[0][row][cc] + red[1][row][cc] + red[2][row][cc] + red[3][row][cc];
  }
}

// ---------------- final batch LayerNorm over y (B,2) ----------------
__global__ __launch_bounds__(1024) void ln_kernel(
    const float* __restrict__ y, const float* __restrict__ g_out, const float* __restrict__ b_out,
    float* __restrict__ out)
{
  __shared__ float wsum[16][4];
  __shared__ float st[4];
  const int t = threadIdx.x;
  float s0 = 0.f, q0 = 0.f, s1 = 0.f, q1 = 0.f;
  for (int r = t; r < B_N; r += 1024) {
    float v0 = y[2*r], v1 = y[2*r + 1];
    s0 += v0; q0 += v0 * v0;
    s1 += v1; q1 += v1 * v1;
  }
  #pragma unroll
  for (int off = 32; off >= 1; off >>= 1) {
    s0 += __shfl_down(s0, off); q0 += __shfl_down(q0, off);
    s1 += __shfl_down(s1, off); q1 += __shfl_down(q1, off);
  }
  if ((t & 63) == 0) { int w = t >> 6; wsum[w][0]=s0; wsum[w][1]=q0; wsum[w][2]=s1; wsum[w][3]=q1; }
  __syncthreads();
  if (t == 0) {
    float S0=0.f,Q0=0.f,S1=0.f,Q1=0.f;
    for (int w = 0; w < 16; ++w) { S0+=wsum[w][0]; Q0+=wsum[w][1]; S1+=wsum[w][2]; Q1+=wsum[w][3]; }
    float n = (float)B_N;
    float mu0 = S0 / n, var0 = Q0 / n - mu0 * mu0;
    float mu1 = S1 / n, var1 = Q1 / n - mu1 * mu1;
    st[0] = mu0; st[1] = rsqrtf(var0 + EPS_F);
    st[2] = mu1; st[3] = rsqrtf(var1 + EPS_F);
  }
  __syncthreads();
  float g0 = g_out[0], g1 = g_out[1], bo0 = b_out[0], bo1 = b_out[1];
  float mu0 = st[0], rs0 = st[1], mu1 = st[2], rs1 = st[3];
  for (int r = t; r < B_N; r += 1024) {
    out[2*r]     = (y[2*r]     - mu0) * rs0 * g0 + bo0;
    out[2*r + 1] = (y[2*r + 1] - mu1) * rs1 * g1 + bo1;
  }
}

extern "C" void kernel_launch(void* const* d_in, const int* in_sizes, int n_in,
                              void* d_out, int out_size, void* d_ws, size_t ws_size,
                              hipStream_t stream) {
  (void)in_sizes; (void)n_in; (void)out_size; (void)ws_size;
  const float* x    = (const float*)d_in[0];
  // d_in[1] = h_0 (unused by the reference)
  const float* Wr   = (const float*)d_in[2];
  const float* Wi   = (const float*)d_in[3];
  const float* Wfr  = (const float*)d_in[4];
  const float* Wfi  = (const float*)d_in[5];
  const float* g_in = (const float*)d_in[6];
  const float* b_in = (const float*)d_in[7];
  const float* g_out= (const float*)d_in[8];
  const float* b_out= (const float*)d_in[9];
  float* out = (float*)d_out;

  char* ws = (char*)d_ws;
  float* AC    = (float*)(ws + 128);          // 32 f: A[16], C[16]
  float* RWr   = (float*)(ws + 256);          // 2048 f
  float* RWi   = (float*)(ws + 256 + 8192);
  float* Kr    = (float*)(ws + 256 + 16384);
  float* Ki    = (float*)(ws + 256 + 24576);
  float* y     = (float*)(ws + 33024);        // 32768 f (B x 2)
  // partials overlaps wp: finalize consumes it BEFORE wprep writes wp (same stream order)
  float* partials = (float*)(ws + 164096);    // 2048*32 f = 256 KB
  unsigned short* wp = (unsigned short*)(ws + 164096);                // 2 MB, chunk-granule layout
  unsigned short* xplan = (unsigned short*)(ws + 2261248);            // 128 MB: 16 planes of P_N bf16

  pass1_kernel<<<2048, 256, 0, stream>>>(x, xplan, partials);
  finalize_kernel<<<1, 1024, 0, stream>>>(partials, g_in, b_in, AC);
  wprep_kernel<<<2048, 256, 0, stream>>>(Wr, Wi, wp, RWr, RWi);
  kterm_kernel<<<8, 256, 0, stream>>>(AC, RWr, RWi, Kr, Ki);
  main_kernel<<<B_N / 32, 256, 0, stream>>>(xplan, wp, AC, Kr, Ki, Wfr, Wfi, y);
  ln_kernel<<<1, 1024, 0, stream>>>(y, g_out, b_out, out);
}

// Round 8
// 238.561 us; speedup vs baseline: 1.0493x; 1.0493x over previous
//
#include <hip/hip_runtime.h>
#include <stdint.h>

#define B_N   16384
#define S_N   256
#define NCH   8
#define P_N   (B_N * S_N)      // 4194304 positions (b,s)
#define EPS_F 1e-5f

typedef float  f32x4  __attribute__((ext_vector_type(4)));
typedef float  f32x16 __attribute__((ext_vector_type(16)));
typedef __bf16 bf16x8 __attribute__((ext_vector_type(8)));
typedef unsigned int u32x4 __attribute__((ext_vector_type(4)));

static __device__ __forceinline__ unsigned short f2bf(float f) {
  union { float f; unsigned u; } v; v.f = f;
  unsigned u = v.u;
  u += 0x7fffu + ((u >> 16) & 1u);          // RNE
  return (unsigned short)(u >> 16);
}
static __device__ __forceinline__ float bf2f(unsigned short h) {
  union { unsigned u; float f; } v; v.u = ((unsigned)h) << 16;
  return v.f;
}

typedef const __attribute__((address_space(1))) unsigned int* gas1_t;
typedef __attribute__((address_space(3))) unsigned int* las3_t;
// async global->LDS, 16B per lane; LDS dest must be linear (base + lane*16)
static __device__ __forceinline__ void gl16(const void* g, void* l) {
  __builtin_amdgcn_global_load_lds((gas1_t)(uintptr_t)g,
                                   (las3_t)(unsigned int)(uintptr_t)l, 16, 0, 0);
}

// ---------------- pass 1: per-channel stats partials + planar bf16 transpose ----------------
__global__ __launch_bounds__(256) void pass1_kernel(
    const float* __restrict__ x, unsigned short* __restrict__ xplan,
    float* __restrict__ partials)
{
  __shared__ float ps[4][32];
  const int t = threadIdx.x;
  const int q = t & 3;               // channel quad: interleaved channels 4q..4q+3
  const int pg = t >> 2;             // 0..63 position-group within tile
  float s[4] = {0.f,0.f,0.f,0.f}, ss[4] = {0.f,0.f,0.f,0.f};
  const f32x4* xv = (const f32x4*)x;

  for (int it = 0; it < 4; ++it) {
    size_t p0 = ((size_t)blockIdx.x * 4 + it) * 512 + (size_t)pg * 8;
    f32x4 v[8];
    #pragma unroll
    for (int j = 0; j < 8; ++j) v[j] = xv[(p0 + j) * 4 + q];
    #pragma unroll
    for (int j = 0; j < 8; ++j)
      #pragma unroll
      for (int k = 0; k < 4; ++k) { s[k] += v[j][k]; ss[k] += v[j][k] * v[j][k]; }
    #pragma unroll
    for (int j2 = 0; j2 < 4; ++j2) {
      u32x4 w;
      #pragma unroll
      for (int k = 0; k < 4; ++k)
        w[k] = (unsigned)f2bf(v[2*k][j2]) | ((unsigned)f2bf(v[2*k+1][j2]) << 16);
      *(u32x4*)(xplan + (size_t)(q * 4 + j2) * P_N + p0) = w;
    }
  }

  #pragma unroll
  for (int off = 32; off >= 4; off >>= 1) {
    #pragma unroll
    for (int k = 0; k < 4; ++k) { s[k] += __shfl_down(s[k], off); ss[k] += __shfl_down(ss[k], off); }
  }
  const int lane = t & 63, wid = t >> 6;
  if (lane < 4) {
    #pragma unroll
    for (int k = 0; k < 4; ++k) {
      ps[wid][lane * 4 + k]      = s[k];
      ps[wid][16 + lane * 4 + k] = ss[k];
    }
  }
  __syncthreads();
  if (t < 32)
    partials[blockIdx.x * 32 + t] = ps[0][t] + ps[1][t] + ps[2][t] + ps[3][t];
}

// ---------------- finalize: reduce partials -> A,C ----------------
__global__ __launch_bounds__(1024) void finalize_kernel(
    const float* __restrict__ partials, const float* __restrict__ g_in,
    const float* __restrict__ b_in, float* __restrict__ AC)
{
  __shared__ float acc[32][32];
  const int t = threadIdx.x;
  const int v = t & 31, chunk = t >> 5;
  float s = 0.f;
  for (int i = 0; i < 64; ++i)
    s += partials[(size_t)(chunk * 64 + i) * 32 + v];
  acc[chunk][v] = s;
  __syncthreads();
  if (t < 32) {
    float tot = 0.f;
    #pragma unroll
    for (int k = 0; k < 32; ++k) tot += acc[k][t];
    acc[0][t] = tot;
  }
  __syncthreads();
  if (t < 16) {
    float n = (float)P_N;
    float mu  = acc[0][t] / n;
    float var = acc[0][16 + t] / n - mu * mu;
    float A = g_in[t] * rsqrtf(var + EPS_F);
    AC[t] = A;
    AC[16 + t] = b_in[t] - mu * A;
  }
}

// ---------------- W prep: fp32 -> bf16, per-wave-register-fragment layout + rowsums -------------
// wrp/wip[c][ow8][u16][kh2][o31:32][j8]: a wave's wreg[u] load = two contiguous 512B runs.
__global__ __launch_bounds__(256) void wprep_kernel(
    const float* __restrict__ Wr, const float* __restrict__ Wi,
    unsigned short* __restrict__ wrp, unsigned short* __restrict__ wip,
    float* __restrict__ RWr, float* __restrict__ RWi)
{
  __shared__ float sr[4], si[4];
  const int row = blockIdx.x, t = threadIdx.x;   // row = c*256 + o, t = k
  const int c = row >> 8, o = row & 255;
  const int ow = o >> 5, o31 = o & 31;
  const size_t idx = (size_t)row * 256 + t;
  float vr = Wr[idx], vi = Wi[idx];
  const int u = t >> 4, kh = (t >> 3) & 1, j = t & 7;
  const size_t widx = ((((size_t)(c * 8 + ow) * 16 + u) * 2 + kh) * 32 + o31) * 8 + j;
  wrp[widx] = f2bf(vr);
  wip[widx] = f2bf(vi);
  float rr = vr, ri = vi;
  #pragma unroll
  for (int off = 32; off >= 1; off >>= 1) { rr += __shfl_down(rr, off); ri += __shfl_down(ri, off); }
  if ((t & 63) == 0) { sr[t >> 6] = rr; si[t >> 6] = ri; }
  __syncthreads();
  if (t == 0) {
    RWr[row] = sr[0] + sr[1] + sr[2] + sr[3];
    RWi[row] = si[0] + si[1] + si[2] + si[3];
  }
}

// ---------------- K terms ----------------
__global__ __launch_bounds__(256) void kterm_kernel(
    const float* __restrict__ AC, const float* __restrict__ RWr, const float* __restrict__ RWi,
    float* __restrict__ Kr, float* __restrict__ Ki)
{
  int idx = blockIdx.x * 256 + threadIdx.x;   // 2048 = c*256+o
  int c = idx >> 8;
  float Ci_ = AC[16 + 2*c], Cq_ = AC[16 + 2*c + 1];
  Kr[idx] = Ci_ * RWr[idx] - Cq_ * RWi[idx];
  Ki[idx] = Cq_ * RWr[idx] + Ci_ * RWi[idx];
}

// X tile stage: 32 rows x 256 k x 2 planes = 32 KB; 4 gl16/thread; granule XOR row&7 swizzle
static __device__ __forceinline__ void stage_x(
    const unsigned short* __restrict__ xplan, int c, int r0, char* buf, int t)
{
  #pragma unroll
  for (int i = 0; i < 4; ++i) {
    const int pl = i >> 1;
    const int row = (i & 1) * 16 + (t >> 5);
    const int g = (t & 31) ^ (row & 7);
    const char* gsrc = (const char*)xplan +
      (((size_t)(2 * c + pl) * P_N + (size_t)(r0 + row) * 256 + g * 8) << 1);
    gl16(gsrc, buf + pl * 16384 + row * 512 + (t & 31) * 16);
  }
}

// ---------------- main: W resident in registers; X streamed via dbuf LDS ----------------
// grid 512 = 8 channels x 64 row-groups; block 512 thr (8 waves, wave w owns o=w*32..w*32+31);
// per wave: 128 VGPRs of W (16 k-frags x 2 types), K=256 fully unrolled, 2 barriers per 32-row tile.
__global__ __launch_bounds__(512, 2) void main_kernel(
    const unsigned short* __restrict__ xplan,
    const unsigned short* __restrict__ wrp,
    const unsigned short* __restrict__ wip,
    const float* __restrict__ AC,
    const float* __restrict__ Kr, const float* __restrict__ Ki,
    const float* __restrict__ Wfr, const float* __restrict__ Wfi,
    float* __restrict__ pacc)
{
  __shared__ char X[2][32768];
  __shared__ float red[8][32][2];

  const int t = threadIdx.x;
  const int w = t >> 6, lane = t & 63;
  const int o31 = lane & 31, kh = lane >> 5;
  const int c = blockIdx.x & 7;
  const int b0 = (blockIdx.x >> 3) * 256;

  const int o = w * 32 + o31;
  const int gidx = c * 256 + o;
  const float kr = Kr[gidx], ki = Ki[gidx];
  const float wfr = Wfr[gidx], wfi = Wfi[gidx];
  const float Ai = AC[2*c], Aq = AC[2*c + 1];
  const float Ci = AC[16 + 2*c], Cq = AC[16 + 2*c + 1];

  // ---- W into registers: 32 KB per wave, coalesced 1KB segments per frag ----
  bf16x8 wr8[16], wi8[16];
  {
    const char* wb  = (const char*)wrp + (size_t)(c * 8 + w) * 16384 + kh * 512 + o31 * 16;
    const char* wib = (const char*)wip + (size_t)(c * 8 + w) * 16384 + kh * 512 + o31 * 16;
    #pragma unroll
    for (int u = 0; u < 16; ++u) {
      wr8[u] = *(const bf16x8*)(wb  + u * 1024);
      wi8[u] = *(const bf16x8*)(wib + u * 1024);
    }
  }

  stage_x(xplan, c, b0, X[0], t);

  #pragma unroll 1
  for (int tile = 0; tile < 8; ++tile) {
    __builtin_amdgcn_s_barrier();          // all waves done reading X[(tile+1)&1] (prev use)
    if (tile + 1 < 8) {
      stage_x(xplan, c, b0 + (tile + 1) * 32, X[(tile + 1) & 1], t);
      asm volatile("s_waitcnt vmcnt(4)" ::: "memory");   // tile's 4 (and W at tile 0) landed
    } else {
      asm volatile("s_waitcnt vmcnt(0)" ::: "memory");
    }
    __builtin_amdgcn_sched_barrier(0);

    const char* Xb = (const char*)X[tile & 1];
    f32x16 arr, aqr, ari, aqi;
    #pragma unroll
    for (int e = 0; e < 16; ++e) { arr[e]=0.f; aqr[e]=0.f; ari[e]=0.f; aqi[e]=0.f; }

    __builtin_amdgcn_s_setprio(1);
    #pragma unroll
    for (int u = 0; u < 16; ++u) {
      const int ga = (((u * 2 + kh) ^ (o31 & 7)) << 4);
      bf16x8 xi8 = *(const bf16x8*)(Xb + o31 * 512 + ga);
      bf16x8 xq8 = *(const bf16x8*)(Xb + 16384 + o31 * 512 + ga);
      arr = __builtin_amdgcn_mfma_f32_32x32x16_bf16(xi8, wr8[u], arr, 0,0,0);
      aqr = __builtin_amdgcn_mfma_f32_32x32x16_bf16(xq8, wr8[u], aqr, 0,0,0);
      ari = __builtin_amdgcn_mfma_f32_32x32x16_bf16(xi8, wi8[u], ari, 0,0,0);
      aqi = __builtin_amdgcn_mfma_f32_32x32x16_bf16(xq8, wi8[u], aqi, 0,0,0);
    }
    __builtin_amdgcn_s_setprio(0);

    // epilogue: amp2 fold + per-q immediate o-reduction (keeps live regs small)
    #pragma unroll
    for (int q = 0; q < 16; ++q) {
      const int brow = (q & 3) + 8 * (q >> 2) + 4 * kh;   // m74/m101 C/D row
      const int ge = ((((o >> 3) ^ (brow & 7)) << 4)) + (o & 7) * 2;
      float xiv = Ai * bf2f(*(const unsigned short*)(Xb + brow * 512 + ge)) + Ci;
      float xqv = Aq * bf2f(*(const unsigned short*)(Xb + 16384 + brow * 512 + ge)) + Cq;
      float amp = xiv * xiv + xqv * xqv;
      float cr  = Ai * arr[q] - Aq * aqi[q] + kr;
      float ci_ = Aq * aqr[q] + Ai * ari[q] + ki;
      float p0 = amp * (cr * wfr - ci_ * wfi);
      float p1 = amp * (ci_ * wfr + cr * wfi);
      #pragma unroll
      for (int off = 1; off < 32; off <<= 1) {
        p0 += __shfl_xor(p0, off);
        p1 += __shfl_xor(p1, off);
      }
      if (o31 == 0) { red[w][brow][0] = p0; red[w][brow][1] = p1; }
    }
    __builtin_amdgcn_s_barrier();          // red complete
    if (t < 64) {
      const int row = t >> 1, cc = t & 1;
      float v = 0.f;
      #pragma unroll
      for (int ww = 0; ww < 8; ++ww) v += red[ww][row][cc];
      pacc[((size_t)c * B_N + b0 + tile * 32 + row) * 2 + cc] = v;
    }
  }
}

// ---------------- final LN, 3 stages ----------------
__global__ __launch_bounds__(256) void ln_a_kernel(
    const float* __restrict__ pacc, float* __restrict__ y, float* __restrict__ spart)
{
  __shared__ float ws_[4][4];
  const int t = threadIdx.x;
  const int r = blockIdx.x * 256 + t;
  float v0 = 0.f, v1 = 0.f;
  #pragma unroll
  for (int c = 0; c < 8; ++c) {
    v0 += pacc[((size_t)c * B_N + r) * 2];
    v1 += pacc[((size_t)c * B_N + r) * 2 + 1];
  }
  y[r * 2] = v0; y[r * 2 + 1] = v1;
  float s0 = v0, q0 = v0 * v0, s1 = v1, q1 = v1 * v1;
  #pragma unroll
  for (int off = 32; off >= 1; off >>= 1) {
    s0 += __shfl_down(s0, off); q0 += __shfl_down(q0, off);
    s1 += __shfl_down(s1, off); q1 += __shfl_down(q1, off);
  }
  if ((t & 63) == 0) { int wv = t >> 6; ws_[wv][0]=s0; ws_[wv][1]=q0; ws_[wv][2]=s1; ws_[wv][3]=q1; }
  __syncthreads();
  if (t < 4)
    spart[blockIdx.x * 4 + t] = ws_[0][t] + ws_[1][t] + ws_[2][t] + ws_[3][t];
}

__global__ void ln_b_kernel(const float* __restrict__ spart, float* __restrict__ st)
{
  const int t = threadIdx.x;            // 64 threads
  const int q = t & 3, i0 = t >> 2;     // 16 row-groups x 4 components
  float s = 0.f;
  #pragma unroll
  for (int i = 0; i < 4; ++i) s += spart[(i0 + i * 16) * 4 + q];
  s += __shfl_down(s, 32); s += __shfl_down(s, 16);
  s += __shfl_down(s, 8);  s += __shfl_down(s, 4);
  if (t < 4) {
    // t==q: s = total component q: {S0,Q0,S1,Q1}
    float n = (float)B_N;
    // compute via lane exchange: need pairs; do it scalar-ish with shfl
    float S0 = __shfl(s, 0), Q0 = __shfl(s, 1), S1 = __shfl(s, 2), Q1 = __shfl(s, 3);
    if (t == 0) {
      float mu0 = S0 / n, var0 = Q0 / n - mu0 * mu0;
      float mu1 = S1 / n, var1 = Q1 / n - mu1 * mu1;
      st[0] = mu0; st[1] = rsqrtf(var0 + EPS_F);
      st[2] = mu1; st[3] = rsqrtf(var1 + EPS_F);
    }
  }
}

__global__ __launch_bounds__(256) void ln_c_kernel(
    const float* __restrict__ y, const float* __restrict__ st,
    const float* __restrict__ g_out, const float* __restrict__ b_out,
    float* __restrict__ out)
{
  const int i = blockIdx.x * 256 + threadIdx.x;   // 32768 values
  const int cc = i & 1;
  out[i] = (y[i] - st[cc * 2]) * st[cc * 2 + 1] * g_out[cc] + b_out[cc];
}

extern "C" void kernel_launch(void* const* d_in, const int* in_sizes, int n_in,
                              void* d_out, int out_size, void* d_ws, size_t ws_size,
                              hipStream_t stream) {
  (void)in_sizes; (void)n_in; (void)out_size; (void)ws_size;
  const float* x    = (const float*)d_in[0];
  // d_in[1] = h_0 (unused by the reference)
  const float* Wr   = (const float*)d_in[2];
  const float* Wi   = (const float*)d_in[3];
  const float* Wfr  = (const float*)d_in[4];
  const float* Wfi  = (const float*)d_in[5];
  const float* g_in = (const float*)d_in[6];
  const float* b_in = (const float*)d_in[7];
  const float* g_out= (const float*)d_in[8];
  const float* b_out= (const float*)d_in[9];
  float* out = (float*)d_out;

  char* ws = (char*)d_ws;
  float* AC    = (float*)(ws + 128);              // 32 f
  float* RWr   = (float*)(ws + 256);              // 8 KB
  float* RWi   = (float*)(ws + 8448);
  float* Kr    = (float*)(ws + 16640);
  float* Ki    = (float*)(ws + 24832);
  float* spart = (float*)(ws + 33024);            // 64*4 f
  float* st    = (float*)(ws + 34048);            // 4 f
  float* y     = (float*)(ws + 36864);            // 128 KB -> 167936
  unsigned short* wrp = (unsigned short*)(ws + 167936);               // 1 MB
  unsigned short* wip = (unsigned short*)(ws + 167936 + 1048576);     // 1 MB
  float* pacc  = (float*)(ws + 2265088);          // 8*16384*2 f = 1 MB
  // pass1 partials overlap pacc (finalize consumes before main writes pacc)
  float* partials = (float*)(ws + 2265088);       // 256 KB
  unsigned short* xplan = (unsigned short*)(ws + 3313664);            // 128 MB

  pass1_kernel<<<2048, 256, 0, stream>>>(x, xplan, partials);
  finalize_kernel<<<1, 1024, 0, stream>>>(partials, g_in, b_in, AC);
  wprep_kernel<<<2048, 256, 0, stream>>>(Wr, Wi, wrp, wip, RWr, RWi);
  kterm_kernel<<<8, 256, 0, stream>>>(AC, RWr, RWi, Kr, Ki);
  main_kernel<<<512, 512, 0, stream>>>(xplan, wrp, wip, AC, Kr, Ki, Wfr, Wfi, pacc);
  ln_a_kernel<<<64, 256, 0, stream>>>(pacc, y, spart);
  ln_b_kernel<<<1, 64, 0, stream>>>(spart, st);
  ln_c_kernel<<<128, 256, 0, stream>>>(y, st, g_out, b_out, out);
}